// Round 14
// baseline (332.202 us; speedup 1.0000x reference)
//
#include <hip/hip_runtime.h>
#include <hip/hip_bf16.h>
#include <stdint.h>

// Problem constants (fixed by reference)
#define TOKENS_C 8192
#define NIN_C    4096
#define NOUT_C   4096
#define GROUP_C  128
#define QZERO_C  8

typedef float   f32x4  __attribute__((ext_vector_type(4)));
typedef int     i32x4  __attribute__((ext_vector_type(4)));

#define GAS __attribute__((address_space(1)))
#define LAS __attribute__((address_space(3)))

__device__ __forceinline__ void gload16(const void* g, void* l) {
  __builtin_amdgcn_global_load_lds((const GAS void*)g, (LAS void*)l, 16, 0, 0);
}

// ---------------- pass 1a: per-token quantize x -> i8 + sx -------------------
__global__ __launch_bounds__(256) void quant_x_kernel(
    const float* __restrict__ x, char* __restrict__ x8, float* __restrict__ sx)
{
  const int t   = blockIdx.x;
  const int tid = threadIdx.x;
  const float* xr = x + (size_t)t * NIN_C;
  f32x4 v[4];
#pragma unroll
  for (int r = 0; r < 4; ++r) v[r] = *(const f32x4*)(xr + tid * 16 + r * 4);
  float m = 0.f;
#pragma unroll
  for (int r = 0; r < 4; ++r)
#pragma unroll
    for (int e = 0; e < 4; ++e) m = fmaxf(m, fabsf(v[r][e]));
#pragma unroll
  for (int off = 32; off >= 1; off >>= 1) m = fmaxf(m, __shfl_xor(m, off));
  __shared__ float wmax[4];
  if ((tid & 63) == 0) wmax[tid >> 6] = m;
  __syncthreads();
  m = fmaxf(fmaxf(wmax[0], wmax[1]), fmaxf(wmax[2], wmax[3]));
  m = fmaxf(m, 1e-20f);
  const float inv = 127.0f / m;
  if (tid == 0) sx[t] = m / 127.0f;
  i32x4 o;
#pragma unroll
  for (int r = 0; r < 4; ++r) {
    int q0 = (int)rintf(v[r][0] * inv), q1 = (int)rintf(v[r][1] * inv);
    int q2 = (int)rintf(v[r][2] * inv), q3 = (int)rintf(v[r][3] * inv);
    o[r] = (q0 & 255) | ((q1 & 255) << 8) | ((q2 & 255) << 16) | ((q3 & 255) << 24);
  }
  *(i32x4*)(x8 + (size_t)t * NIN_C + tid * 16) = o;
}

// ---------------- pass 1b: repack qweight (int32 codes) -> i8 (q-8) ----------
__global__ __launch_bounds__(256) void repack_w_kernel(
    const int* __restrict__ qw, char* __restrict__ w8)
{
  const size_t base = ((size_t)blockIdx.x * 256 + threadIdx.x) * 16;
  i32x4 o;
#pragma unroll
  for (int r = 0; r < 4; ++r) {
    i32x4 q = *(const i32x4*)(qw + base + r * 4);
    o[r] = ((q[0] - QZERO_C) & 255) | (((q[1] - QZERO_C) & 255) << 8) |
           (((q[2] - QZERO_C) & 255) << 16) | (((q[3] - QZERO_C) & 255) << 24);
  }
  *(i32x4*)(w8 + base) = o;
}

// ---------------- pass 1c: transpose scales [NOUT][32] -> sT[32][NOUT] -------
__global__ __launch_bounds__(256) void tsc_kernel(
    const float* __restrict__ sc, float* __restrict__ sT)
{
  const int id = blockIdx.x * 256 + threadIdx.x;   // over 32*4096
  const int o = id & (NOUT_C - 1), g = id >> 12;
  sT[id] = sc[o * (NIN_C / GROUP_C) + g];
}

// ---------------- pass 2: i8 GEMM ---------------------------------------------
// R13 counters: 2nd 1024-thread block never co-resided (Occ stuck 45%) ->
// single block + per-tile WAITV(0) drain = latency-bound (all pipes <50%).
// R14 geometry guarantees dual-occupancy AND counted vmcnt:
//   256x128 tile, 512 threads (8 waves 4Mx2N, wave-tile 64x64 -> same 64-reg
//   footprint R13 proved), ring-3 LDS of 24KB slots (A 16KB + B 8KB) = 72KB
//   -> 2 blocks/CU (144KB LDS, 1024 thr = half the CU limit), 4 waves/SIMD.
//   Ring-3: compute slot t%3, stage tile t+2 into slot (t+2)%3 (= slot of
//   t-1, freed at t-1's end barrier). WAITV(3) per tile — never 0:
//   entering t in-flight [STG(t+1)=3]; +LD_S(4, even t)+STG(t+2)=3;
//   WAITV(3) retires STG(t+1)(+LD_S), keeps STG(t+2).
// Swizzle (R12-verified), APPLY, fenced transposed epilogue: unchanged.
#define BM 256
#define BN 128
#define BKB 64
#define NT (NIN_C / BKB)           // 64 tiles
#define SLOT_SZ 24576              // 16KB A + 8KB B

__global__ __launch_bounds__(512, 4) void gemm_i8_kernel(
    const char* __restrict__ Ag,   // x8 [M][K] i8
    const char* __restrict__ Bg,   // w8 [N][K] i8
    const float* __restrict__ sTg, // [32][NOUT]
    const float* __restrict__ sx,  // [M]
    float* __restrict__ C)         // [M][N] f32
{
  constexpr int N = NOUT_C, KB = NIN_C;
  __shared__ char smem[3 * SLOT_SZ];   // 72KB

  const int tid  = threadIdx.x;
  const int lane = tid & 63;
  const int wid  = tid >> 6;       // 0..7
  const int wm   = wid >> 1;       // 0..3 -> 64 rows of C
  const int wn   = wid & 1;        // 0..1 -> 64 cols of C
  const int bm   = blockIdx.x;
  const int bn   = blockIdx.y;

  const int frow  = lane & 15;
  const int klane = lane >> 4;     // 0..3

  // staging: A = 256 rows x 64B: thread covers rows tid>>2 and 128+(tid>>2),
  // granule tid&3. B = 128 rows x 64B: row tid>>2, granule tid&3.
  // LDS dest LINEAR; source granule pre-swizzled g ^= (row>>1)&3 = (tid>>3)&3.
  const int gsrc = ((tid & 3) ^ ((tid >> 3) & 3)) * 16;
  const uint32_t aoff0 = (uint32_t)((bm * BM + (tid >> 2)) * KB + gsrc);
  const uint32_t aoff1 = (uint32_t)((bm * BM + 128 + (tid >> 2)) * KB + gsrc);
  const uint32_t boff  = (uint32_t)((bn * BN + (tid >> 2)) * KB + gsrc);
  const int sdst = tid * 16;

  // STG = 3 gload instructions (vmcnt ledger counts 3 per stage)
#define STG(tt, SW) { char* d_ = smem + (SW) * SLOT_SZ + sdst;                 \
    gload16(Ag + aoff0 + (uint32_t)(tt) * BKB, d_);                            \
    gload16(Ag + aoff1 + (uint32_t)(tt) * BKB, d_ + 8192);                     \
    gload16(Bg + boff  + (uint32_t)(tt) * BKB, d_ + 16384); }

  const int ccol0 = bn * BN + wn * 64;
  const int scoff = ccol0 + frow;
#define LD_S(dst, g)                                                           \
  _Pragma("unroll")                                                            \
  for (int j_ = 0; j_ < 4; ++j_)                                               \
    dst[j_] = sTg[(size_t)(g) * NOUT_C + scoff + j_ * 16];

  // fragment read bases with matching XOR swizzle (R12-verified formula)
  const int kswz = (klane ^ ((frow >> 1) & 3)) << 4;
  const int ard0 = (wm * 64 + frow) * 64 + kswz;           // + ii*1024
  const int brd0 = 16384 + (wn * 64 + frow) * 64 + kswz;   // + j*1024

  f32x4 facc[4][4] = {};
  const i32x4 zq = {0, 0, 0, 0};

#define MFI(a_, b_, c_) __builtin_amdgcn_mfma_i32_16x16x64_i8(a_, b_, c_, 0, 0, 0)
#define APPLY(ii, jj, pv, scur)                                                \
  { f32x4 tf_;                                                                 \
    tf_[0] = (float)(pv)[0]; tf_[1] = (float)(pv)[1];                          \
    tf_[2] = (float)(pv)[2]; tf_[3] = (float)(pv)[3];                          \
    facc[ii][jj] += tf_ * (scur)[jj]; }
#define BAR __builtin_amdgcn_s_barrier()
#define WAITV(n) asm volatile("s_waitcnt vmcnt(" #n ")" ::: "memory")
#define SBAR0 __builtin_amdgcn_sched_barrier(0)

  // One tile: LD_S (even tiles) -> STG(t+2 into slot (t+2)%3) -> 4 bf reads
  // -> 4x{ak read, 4 MFMA, 4 apply} -> WAITV(WVN) -> barrier.
#define TILE(tt, SLOT, scur, DO_LDS, snxt, gnxt, DO_STG, WVN)                  \
  {                                                                            \
    const char* As_ = smem + (SLOT) * SLOT_SZ;                                 \
    if (DO_LDS) { LD_S(snxt, gnxt); }                                          \
    if (DO_STG) { STG((tt) + 2, ((tt) + 2) % 3); }                             \
    i32x4 bf0 = *(const i32x4*)(As_ + brd0);                                   \
    i32x4 bf1 = *(const i32x4*)(As_ + brd0 + 1024);                            \
    i32x4 bf2 = *(const i32x4*)(As_ + brd0 + 2048);                            \
    i32x4 bf3 = *(const i32x4*)(As_ + brd0 + 3072);                            \
    _Pragma("unroll")                                                          \
    for (int ii = 0; ii < 4; ++ii) {                                           \
      i32x4 ak = *(const i32x4*)(As_ + ard0 + ii * 1024);                      \
      i32x4 p0, p1, p2, p3;                                                    \
      p0 = MFI(ak, bf0, zq); p1 = MFI(ak, bf1, zq);                            \
      p2 = MFI(ak, bf2, zq); p3 = MFI(ak, bf3, zq);                            \
      APPLY(ii, 0, p0, scur); APPLY(ii, 1, p1, scur);                          \
      APPLY(ii, 2, p2, scur); APPLY(ii, 3, p3, scur);                          \
    }                                                                          \
    WAITV(WVN); SBAR0; BAR;                                                    \
  }

  float sA[4], sB[4];

  // ---- prologue: s(0) first (oldest), stage tiles 0,1 into slots 0,1 ----
  // queue = [LD:4, STG0:3, STG1:3] = 10; WAITV(3) retires LD+STG0, keeps STG1.
  LD_S(sA, 0);
  SBAR0;
  STG(0, 0); STG(1, 1);
  WAITV(3);
  BAR; SBAR0;

  // ---- main loop: 12 tiles/iter (slot period 3 x scale period 4).
  // Group g = t/2; scale buffers alternate per group (sA even-g, sB odd-g);
  // next group's scale loaded at the first tile of the current group.
  for (int t0 = 0; t0 < 60; t0 += 12) {
    const int g0 = t0 >> 1;
    TILE(t0 + 0,  0, sA, 1, sB, g0 + 1, 1, 3);
    TILE(t0 + 1,  1, sA, 0, sB, 0,      1, 3);
    TILE(t0 + 2,  2, sB, 1, sA, g0 + 2, 1, 3);
    TILE(t0 + 3,  0, sB, 0, sA, 0,      1, 3);
    TILE(t0 + 4,  1, sA, 1, sB, g0 + 3, 1, 3);
    TILE(t0 + 5,  2, sA, 0, sB, 0,      1, 3);
    TILE(t0 + 6,  0, sB, 1, sA, g0 + 4, 1, 3);
    TILE(t0 + 7,  1, sB, 0, sA, 0,      1, 3);
    TILE(t0 + 8,  2, sA, 1, sB, g0 + 5, 1, 3);
    TILE(t0 + 9,  0, sA, 0, sB, 0,      1, 3);
    TILE(t0 + 10, 1, sB, 1, sA, g0 + 6, 1, 3);
    TILE(t0 + 11, 2, sB, 0, sA, 0,      1, 3);
  }
  // ---- peel tiles 60..63 (groups 30,31; sA=s30 entering, load sB=s31) ----
  TILE(60, 0, sA, 1, sB, 31, 1, 3);   // stages STG(62, slot 2)
  TILE(61, 1, sA, 0, sB, 0,  1, 3);   // stages STG(63, slot 0)
  TILE(62, 2, sB, 0, sA, 0,  0, 0);   // drain: STG(63) must land
  TILE(63, 0, sB, 0, sA, 0,  0, 0);   // final BAR guards epilogue smem reuse

  // ---- epilogue: transposed through LDS (fenced — R12-verified).
  // Per fi: scatter 16x64 block (sx applied) into wave-private 4KB,
  // __syncthreads (orders mixed-type LDS RAW), read row-major, store
  // 256B-contiguous runs; trailing sync guards WAR with next fi.
  const int crow0 = bm * BM + wm * 64;
  const int r0 = klane << 2;
  char* const wb = smem + wid * 4096;   // 8 waves x 4KB = 32KB
#pragma unroll
  for (int fi = 0; fi < 4; ++fi) {
    const f32x4 sxv = *(const f32x4*)(sx + crow0 + fi * 16 + r0);
#pragma unroll
    for (int j = 0; j < 4; ++j) {
      f32x4 v = facc[fi][j];
#pragma unroll
      for (int r = 0; r < 4; ++r)
        *(float*)(wb + (r0 + r) * 256 + (j * 16 + frow) * 4) = v[r] * sxv[r];
    }
    __syncthreads();
#pragma unroll
    for (int sub = 0; sub < 4; ++sub) {
      const int row16 = klane + sub * 4;
      f32x4 v = *(const f32x4*)(wb + row16 * 256 + frow * 16);
      *(f32x4*)(C + (int64_t)(crow0 + fi * 16 + row16) * N + ccol0 + frow * 4) = v;
    }
    __syncthreads();
  }
#undef STG
#undef LD_S
#undef MFI
#undef APPLY
#undef TILE
#undef BAR
#undef WAITV
#undef SBAR0
}

// ---------------- fallback (only if ws too small): naive fp32 ---------------
__global__ __launch_bounds__(256) void naive_kernel(
    const float* __restrict__ x, const int* __restrict__ qw,
    const float* __restrict__ sc, float* __restrict__ out)
{
  const int64_t idx = (int64_t)blockIdx.x * 256 + threadIdx.x;
  const int tok = (int)(idx >> 12);
  const int o   = (int)(idx & 4095);
  const float* xr = x + (int64_t)tok * NIN_C;
  const int* qr = qw + (int64_t)o * NIN_C;
  float acc = 0.f;
  for (int g = 0; g < NIN_C / GROUP_C; ++g) {
    float s = sc[(o << 5) | g];
    float ga = 0.f;
#pragma unroll 4
    for (int i = g * GROUP_C; i < (g + 1) * GROUP_C; ++i)
      ga += xr[i] * (float)(qr[i] - QZERO_C);
    acc += s * ga;
  }
  out[idx] = acc;
}

extern "C" void kernel_launch(void* const* d_in, const int* in_sizes, int n_in,
                              void* d_out, int out_size, void* d_ws, size_t ws_size,
                              hipStream_t stream) {
  const float* x  = (const float*)d_in[0];
  const int*   qw = (const int*)d_in[1];
  const float* sc = (const float*)d_in[2];
  float* out = (float*)d_out;

  const size_t x8_bytes = (size_t)TOKENS_C * NIN_C;          // 32 MiB
  const size_t w8_bytes = (size_t)NOUT_C * NIN_C;            // 16 MiB
  const size_t sx_bytes = (size_t)TOKENS_C * sizeof(float);  // 32 KiB
  const size_t sT_bytes = (size_t)(NIN_C / GROUP_C) * NOUT_C * sizeof(float);

  if (ws_size < x8_bytes + w8_bytes + sx_bytes + sT_bytes) {
    const int64_t total = (int64_t)TOKENS_C * NOUT_C;
    naive_kernel<<<(int)(total / 256), 256, 0, stream>>>(x, qw, sc, out);
    return;
  }

  char*  x8 = (char*)d_ws;
  char*  w8 = (char*)d_ws + x8_bytes;
  float* sx = (float*)((char*)d_ws + x8_bytes + w8_bytes);
  float* sT = (float*)((char*)d_ws + x8_bytes + w8_bytes + sx_bytes);

  quant_x_kernel<<<TOKENS_C, 256, 0, stream>>>(x, x8, sx);
  repack_w_kernel<<<(int)(w8_bytes / 16 / 256), 256, 0, stream>>>(qw, w8);
  tsc_kernel<<<(int)((NIN_C / GROUP_C) * NOUT_C / 256), 256, 0, stream>>>(sc, sT);
  {
    dim3 grid(TOKENS_C / BM, NOUT_C / BN);   // 32 x 32 = 1024 wg
    gemm_i8_kernel<<<grid, 512, 0, stream>>>(x8, w8, sT, sx, out);
  }
}